// Round 1
// baseline (113.454 us; speedup 1.0000x reference)
//
#include <hip/hip_runtime.h>
#include <hip/hip_bf16.h>

#define Bn 64
#define Cn 128
#define Tn 2048
#define Fn 5
#define Nn 640
#define TCHUNK 128
#define NCHUNK (Tn / TCHUNK)   // 16

typedef __attribute__((ext_vector_type(8))) short bf16x8;
typedef __attribute__((ext_vector_type(4))) float f32x4;

// round-to-nearest-even f32 -> bf16 (finite inputs)
__device__ __forceinline__ short f2bf(float f) {
    union { float f; unsigned u; } v; v.f = f;
    unsigned r = (v.u + 0x7fffu + ((v.u >> 16) & 1u)) >> 16;
    return (short)r;
}

// XOR swizzle: spreads rows across bank-quads (G4). row in [0,128), bytecol in [0,256)
__device__ __forceinline__ int swz_off(int row, int bytecol) {
    return (row * 256 + bytecol) ^ ((row & 7) << 4);
}

__global__ __launch_bounds__(512)
void strg_kernel(const float* __restrict__ d0, const float* __restrict__ d1,
                 const float* __restrict__ d2, const float* __restrict__ d3,
                 const float* __restrict__ d4, float* __restrict__ out)
{
    __shared__ short  Xs[Cn * TCHUNK];  // 32 KB swizzled bf16 tile
    __shared__ float  S_lds[Cn];
    __shared__ float  diag[Cn];
    __shared__ float  mrow[Cn];
    __shared__ float  ivrow[Cn];
    __shared__ float  D_lds[Cn];
    __shared__ float  dinv[Cn];

    const int tid = threadIdx.x;
    const int bfid = blockIdx.x;
    const int b = bfid / Fn;
    const int f = bfid - b * Fn;

    const float* src = (f == 0) ? d0 : (f == 1) ? d1 : (f == 2) ? d2 : (f == 3) ? d3 : d4;
    src += (size_t)b * Cn * Tn;

    if (tid < Cn) { S_lds[tid] = 0.0f; D_lds[tid] = 0.0f; }

    // staging mapping: thread covers row (srow + 32i), 8 consecutive f32 at segment sseg
    const int srow = tid >> 4;        // 0..31
    const int sseg = tid & 15;        // 0..15

    // wave mapping: 8 waves in 4x2 grid, each owns a 32x64 tile of Q
    const int lane = tid & 63;
    const int w  = tid >> 6;
    const int wr = w >> 1;            // 0..3
    const int wc = w & 1;             // 0..1
    const int r0 = wr * 32;
    const int c0 = wc * 64;
    const int lg = lane >> 4;         // 0..3
    const int ll = lane & 15;

    f32x4 acc[2][4] = {};
    float psum[4] = {0.f, 0.f, 0.f, 0.f};

    for (int ch = 0; ch < NCHUNK; ++ch) {
        const float* cb = src + ch * TCHUNK;
        #pragma unroll
        for (int i = 0; i < 4; ++i) {
            const int row = i * 32 + srow;
            const float* rp = cb + (size_t)row * Tn + sseg * 8;
            float4 v0 = *(const float4*)rp;
            float4 v1 = *(const float4*)(rp + 4);
            psum[i] += v0.x + v0.y + v0.z + v0.w + v1.x + v1.y + v1.z + v1.w;
            bf16x8 h;
            h[0]=f2bf(v0.x); h[1]=f2bf(v0.y); h[2]=f2bf(v0.z); h[3]=f2bf(v0.w);
            h[4]=f2bf(v1.x); h[5]=f2bf(v1.y); h[6]=f2bf(v1.z); h[7]=f2bf(v1.w);
            *(bf16x8*)((char*)Xs + swz_off(row, sseg * 16)) = h;
        }
        __syncthreads();

        #pragma unroll
        for (int ks = 0; ks < 4; ++ks) {
            bf16x8 afr[2], bfr[4];
            #pragma unroll
            for (int m = 0; m < 2; ++m) {
                const int row = r0 + m * 16 + ll;
                afr[m] = *(const bf16x8*)((const char*)Xs + swz_off(row, ks * 64 + lg * 16));
            }
            #pragma unroll
            for (int n = 0; n < 4; ++n) {
                const int col = c0 + n * 16 + ll;
                bfr[n] = *(const bf16x8*)((const char*)Xs + swz_off(col, ks * 64 + lg * 16));
            }
            #pragma unroll
            for (int m = 0; m < 2; ++m)
                #pragma unroll
                for (int n = 0; n < 4; ++n)
                    acc[m][n] = __builtin_amdgcn_mfma_f32_16x16x32_bf16(afr[m], bfr[n], acc[m][n], 0, 0, 0);
        }
        __syncthreads();
    }

    // fold row-sum partials
    #pragma unroll
    for (int i = 0; i < 4; ++i)
        atomicAdd(&S_lds[i * 32 + srow], psum[i]);

    // extract Gram diagonal (each diag element has exactly one owner lane)
    #pragma unroll
    for (int m = 0; m < 2; ++m)
      #pragma unroll
      for (int n = 0; n < 4; ++n)
        #pragma unroll
        for (int e = 0; e < 4; ++e) {
            const int row = r0 + m * 16 + lg * 4 + e;
            const int col = c0 + n * 16 + ll;
            if (row == col) diag[row] = acc[m][n][e];
        }
    __syncthreads();

    if (tid < Cn) {
        const float S  = S_lds[tid];
        const float mu = S * (1.0f / Tn);
        float var = (diag[tid] - (float)Tn * mu * mu) * (1.0f / (Tn - 1));
        var = var < 0.f ? 0.f : var;
        const float sd = sqrtf(var);
        mrow[tid]  = mu;
        ivrow[tid] = 1.0f / (sd + 1e-8f);
        const size_t ofs = (size_t)Bn * Nn * Nn;
        out[ofs + (size_t)b * Nn + f * Cn + tid] = var;                          // node_features
        out[ofs + (size_t)Bn * Nn + ((size_t)b * Cn + tid) * Fn + f] = var;      // bandpowers
    }
    __syncthreads();

    // per-lane row/col stats
    float mi[2][4], ii[2][4], mj[4], ij[4];
    #pragma unroll
    for (int m = 0; m < 2; ++m)
      #pragma unroll
      for (int e = 0; e < 4; ++e) {
          const int row = r0 + m * 16 + lg * 4 + e;
          mi[m][e] = mrow[row];
          ii[m][e] = ivrow[row];
      }
    #pragma unroll
    for (int n = 0; n < 4; ++n) {
        const int col = c0 + n * 16 + ll;
        mj[n] = mrow[col];
        ij[n] = ivrow[col];
    }

    auto ablk = [&](int m, int n, int e) -> float {
        const int row = r0 + m * 16 + lg * 4 + e;
        const int col = c0 + n * 16 + ll;
        float c = fabsf((acc[m][n][e] - (float)Tn * mi[m][e] * mj[n])
                        * ii[m][e] * ij[n] * (1.0f / (Tn - 1)));
        c = (row == col) ? 1.0f : c;
        const int d = row > col ? row - col : col - row;
        const float spa = (d >= 1 && d <= 3) ? 1.0f : 0.0f;
        return 0.5f * (spa + c);
    };

    // D row sums: each lane sums its 4 cols, reduce across the 16 lanes sharing a row
    #pragma unroll
    for (int m = 0; m < 2; ++m)
      #pragma unroll
      for (int e = 0; e < 4; ++e) {
          float s = 0.f;
          #pragma unroll
          for (int n = 0; n < 4; ++n) s += ablk(m, n, e);
          s += __shfl_xor(s, 1);
          s += __shfl_xor(s, 2);
          s += __shfl_xor(s, 4);
          s += __shfl_xor(s, 8);
          if (ll == 0) atomicAdd(&D_lds[r0 + m * 16 + lg * 4 + e], s);
      }
    __syncthreads();

    if (tid < Cn) dinv[tid] = rsqrtf(D_lds[tid] + 1e-8f);
    __syncthreads();

    float di[2][4], dj[4];
    #pragma unroll
    for (int m = 0; m < 2; ++m)
      #pragma unroll
      for (int e = 0; e < 4; ++e)
          di[m][e] = dinv[r0 + m * 16 + lg * 4 + e];
    #pragma unroll
    for (int n = 0; n < 4; ++n)
        dj[n] = dinv[c0 + n * 16 + ll];

    float* Ab = out + (size_t)b * Nn * Nn;
    const int fc = f * Cn;
    #pragma unroll
    for (int m = 0; m < 2; ++m)
      #pragma unroll
      for (int e = 0; e < 4; ++e) {
          const int row = r0 + m * 16 + lg * 4 + e;
          const size_t rowoff = (size_t)(fc + row) * Nn + fc;
          #pragma unroll
          for (int n = 0; n < 4; ++n) {
              const int col = c0 + n * 16 + ll;
              Ab[rowoff + col] = di[m][e] * ablk(m, n, e) * dj[n];
          }
      }
}

extern "C" void kernel_launch(void* const* d_in, const int* in_sizes, int n_in,
                              void* d_out, int out_size, void* d_ws, size_t ws_size,
                              hipStream_t stream) {
    const float* d0 = (const float*)d_in[0];
    const float* d1 = (const float*)d_in[1];
    const float* d2 = (const float*)d_in[2];
    const float* d3 = (const float*)d_in[3];
    const float* d4 = (const float*)d_in[4];
    float* out = (float*)d_out;

    // A_norm is block-diagonal: zero everything once, then fill the 5 CxC blocks/batch
    hipMemsetAsync(d_out, 0, (size_t)out_size * sizeof(float), stream);

    strg_kernel<<<dim3(Bn * Fn), dim3(512), 0, stream>>>(d0, d1, d2, d3, d4, out);
}